// Round 1
// baseline (581.064 us; speedup 1.0000x reference)
//
#include <hip/hip_runtime.h>
#include <math.h>

// Shapes (fixed by the reference)
#define B_   128
#define W_   512
#define D_   2048
#define H_   16
#define DH_  128

// ---------------------------------------------------------------------------
// Generic fp32 GEMM: C[ks][batch][m][n] (+= slice) = alpha * sum_k A*B
//   A element:  A[batch*abatch + m*am + k]           (ak == 1 always)
//   B element:  B[batch*bbatch + n*bn + k*bk]
//   C element:  C[ks*cslice + batch*cbatch + m*cm + n]
// grid: x = N/64, y = M/64, z = batch_count * ksplit.  K % ksplit == 0,
// (K/ksplit) % 16 == 0, M,N multiples of 64 — guaranteed by all call sites.
// ---------------------------------------------------------------------------
#define KC 16
__global__ __launch_bounds__(256) void gemm_tile(
    const float* __restrict__ A, int am, int abatch,
    const float* __restrict__ Bm, int bn, int bk, int bbatch,
    float* __restrict__ C, int cm, int cbatch, long cslice,
    int K, int ksplit, float alpha)
{
  __shared__ float As[64][KC + 1];   // [m][k]
  __shared__ float Bs[KC][64 + 1];   // [k][n]

  const int t  = threadIdx.x;
  const int tx = t & 15, ty = t >> 4;
  const int n0 = blockIdx.x * 64;
  const int m0 = blockIdx.y * 64;
  const int batch = blockIdx.z / ksplit;
  const int ks    = blockIdx.z % ksplit;
  const int klen  = K / ksplit;
  const int kbeg  = ks * klen;

  const float* Ab = A  + (long)batch * abatch + (long)m0 * am + kbeg;
  const float* Bb = Bm + (long)batch * bbatch + (long)n0 * bn + (long)kbeg * bk;

  float acc[4][4] = {};

  for (int kc = 0; kc < klen; kc += KC) {
    // stage A tile: 64m x 16k
#pragma unroll
    for (int i = 0; i < 4; ++i) {
      int idx = i * 256 + t;
      int m = idx >> 4, k = idx & 15;
      As[m][k] = Ab[(long)m * am + kc + k];
    }
    // stage B tile: 16k x 64n
    if (bk == 1) {
#pragma unroll
      for (int i = 0; i < 4; ++i) {
        int idx = i * 256 + t;
        int n = idx >> 4, k = idx & 15;
        Bs[k][n] = Bb[(long)n * bn + kc + k];
      }
    } else {  // bn == 1, B stored [K][N]
#pragma unroll
      for (int i = 0; i < 4; ++i) {
        int idx = i * 256 + t;
        int k = idx >> 6, n = idx & 63;
        Bs[k][n] = Bb[(long)(kc + k) * bk + n];
      }
    }
    __syncthreads();

#pragma unroll
    for (int kk = 0; kk < KC; ++kk) {
      float a[4], b[4];
#pragma unroll
      for (int i = 0; i < 4; ++i) a[i] = As[ty * 4 + i][kk];
#pragma unroll
      for (int j = 0; j < 4; ++j) b[j] = Bs[kk][tx * 4 + j];
#pragma unroll
      for (int i = 0; i < 4; ++i)
#pragma unroll
        for (int j = 0; j < 4; ++j) acc[i][j] += a[i] * b[j];
    }
    __syncthreads();
  }

  float* Cb = C + (long)ks * cslice + (long)batch * cbatch;
#pragma unroll
  for (int i = 0; i < 4; ++i)
#pragma unroll
    for (int j = 0; j < 4; ++j)
      Cb[(long)(m0 + ty * 4 + i) * cm + (n0 + tx * 4 + j)] = alpha * acc[i][j];
}

// ---------------------------------------------------------------------------
// reduce K-split partials: out[i] = sum_{s<ns} part[s*stride + i]
// ---------------------------------------------------------------------------
__global__ void reduce_add_k(const float* __restrict__ part, int ns, long stride,
                             long n, float* __restrict__ out)
{
  for (long i = (long)blockIdx.x * blockDim.x + threadIdx.x; i < n;
       i += (long)gridDim.x * blockDim.x) {
    float s = 0.f;
    for (int k = 0; k < ns; ++k) s += part[k * stride + i];
    out[i] = s;
  }
}

// ---------------------------------------------------------------------------
// logits[b,h,s] = scale * sum_e qt[b,h,e] * kv[b,s,e]
//   kv[b,s,:] = buffer[b,s+1,:] for s<511, x[b,:] for s==511
// grid (128 b, 2 s-halves), block 256.  Block computes [16 h x 256 s].
// Thread owns 4h x 4s.  K (=e) staged in chunks of 32.
// ---------------------------------------------------------------------------
__global__ __launch_bounds__(256) void logits_k(
    const float* __restrict__ x, const float* __restrict__ buffer,
    const float* __restrict__ qt, float* __restrict__ lg)
{
  __shared__ float kvs[256][33];  // [s_local][e_chunk]
  __shared__ float qts[16][33];   // [h][e_chunk]

  const int b  = blockIdx.x;
  const int sh = blockIdx.y;        // 0..1
  const int t  = threadIdx.x;
  const int hg = t & 3;             // h = hg*4 + i
  const int sg = t >> 2;            // s_local = sg*4 + j

  const float* qtb = qt + (long)b * (H_ * D_);
  float acc[4][4] = {};

  for (int e0 = 0; e0 < D_; e0 += 32) {
    // stage 256 kv rows x 32 e (coalesced: 32 lanes per row)
#pragma unroll
    for (int i = 0; i < 32; ++i) {
      int idx = i * 256 + t;
      int s = idx >> 5, e = idx & 31;
      int s_glob = sh * 256 + s;
      const float* row = (s_glob < W_ - 1)
                           ? buffer + ((long)(b * W_ + s_glob + 1) << 11)
                           : x + ((long)b << 11);
      kvs[s][e] = row[e0 + e];
    }
    // stage qt 16h x 32e
#pragma unroll
    for (int i = 0; i < 2; ++i) {
      int idx = i * 256 + t;
      int h = idx >> 5, e = idx & 31;
      qts[h][e] = qtb[h * D_ + e0 + e];
    }
    __syncthreads();

#pragma unroll
    for (int kk = 0; kk < 32; ++kk) {
      float a[4], v[4];
#pragma unroll
      for (int i = 0; i < 4; ++i) a[i] = qts[hg * 4 + i][kk];
#pragma unroll
      for (int j = 0; j < 4; ++j) v[j] = kvs[sg * 4 + j][kk];
#pragma unroll
      for (int i = 0; i < 4; ++i)
#pragma unroll
        for (int j = 0; j < 4; ++j) acc[i][j] += a[i] * v[j];
    }
    __syncthreads();
  }

  const float scale = 0.088388347648318447f;  // 128^-0.5
#pragma unroll
  for (int i = 0; i < 4; ++i)
#pragma unroll
    for (int j = 0; j < 4; ++j)
      lg[(long)b * (H_ * W_) + (hg * 4 + i) * W_ + sh * 256 + sg * 4 + j] =
          acc[i][j] * scale;
}

// ---------------------------------------------------------------------------
// softmax over s (512) for each (b,h): one wave per row.
// ---------------------------------------------------------------------------
__global__ __launch_bounds__(64) void softmax_k(float* __restrict__ lg)
{
  const int bh = blockIdx.x;      // 0..2047
  const int lane = threadIdx.x;
  float* p = lg + (long)bh * W_;

  float v[8];
  float m = -1e30f;
#pragma unroll
  for (int i = 0; i < 8; ++i) { v[i] = p[i * 64 + lane]; m = fmaxf(m, v[i]); }
#pragma unroll
  for (int off = 32; off; off >>= 1) m = fmaxf(m, __shfl_xor(m, off));
  float s = 0.f;
#pragma unroll
  for (int i = 0; i < 8; ++i) { v[i] = expf(v[i] - m); s += v[i]; }
#pragma unroll
  for (int off = 32; off; off >>= 1) s += __shfl_xor(s, off);
  const float inv = 1.0f / s;
#pragma unroll
  for (int i = 0; i < 8; ++i) p[i * 64 + lane] = v[i] * inv;
}

// ---------------------------------------------------------------------------
// vt[b,h,e] = sum_s attn[b,h,s] * kv[b,s,e]
// grid (128 b, 8 e-tiles of 256), block 256.  Block computes [16 h x 256 e].
// Thread owns 4h x 4e.  s staged in chunks of 32.
// ---------------------------------------------------------------------------
__global__ __launch_bounds__(256) void vtilde_k(
    const float* __restrict__ x, const float* __restrict__ buffer,
    const float* __restrict__ attn, float* __restrict__ vt)
{
  __shared__ float kvs[32][257];  // [s_local][e]
  __shared__ float ats[16][33];   // [h][s_local]

  const int b  = blockIdx.x;
  const int et = blockIdx.y;      // 0..7
  const int t  = threadIdx.x;
  const int hg = t & 3;           // h = hg*4 + i
  const int eg = t >> 2;          // e_local = eg*4 + j

  float acc[4][4] = {};

  for (int sc = 0; sc < W_; sc += 32) {
    // stage 32 kv rows x 256 e (each instruction: 256 consecutive floats... lane t = column)
#pragma unroll
    for (int i = 0; i < 32; ++i) {
      int s_glob = sc + i;
      const float* row = (s_glob < W_ - 1)
                           ? buffer + ((long)(b * W_ + s_glob + 1) << 11)
                           : x + ((long)b << 11);
      kvs[i][t] = row[et * 256 + t];
    }
    // stage attn 16h x 32s
#pragma unroll
    for (int i = 0; i < 2; ++i) {
      int idx = i * 256 + t;
      int h = idx >> 5, s = idx & 31;
      ats[h][s] = attn[(long)b * (H_ * W_) + h * W_ + sc + s];
    }
    __syncthreads();

#pragma unroll
    for (int kk = 0; kk < 32; ++kk) {
      float a[4], v[4];
#pragma unroll
      for (int i = 0; i < 4; ++i) a[i] = ats[hg * 4 + i][kk];
#pragma unroll
      for (int j = 0; j < 4; ++j) v[j] = kvs[kk][eg * 4 + j];
#pragma unroll
      for (int i = 0; i < 4; ++i)
#pragma unroll
        for (int j = 0; j < 4; ++j) acc[i][j] += a[i] * v[j];
    }
    __syncthreads();
  }

#pragma unroll
  for (int i = 0; i < 4; ++i)
#pragma unroll
    for (int j = 0; j < 4; ++j)
      vt[(long)b * (H_ * D_) + (hg * 4 + i) * D_ + et * 256 + eg * 4 + j] =
          acc[i][j];
}

// ---------------------------------------------------------------------------
// gate epilogue: z = sum of 8 partial slices + bg;  y = x + sigmoid(z)*out1
// ---------------------------------------------------------------------------
__global__ __launch_bounds__(256) void gate_final_k(
    const float* __restrict__ part, const float* __restrict__ bg,
    const float* __restrict__ x, const float* __restrict__ out1,
    float* __restrict__ y)
{
  const long i = (long)blockIdx.x * 256 + threadIdx.x;  // 0..262143
  float z = bg[i & (D_ - 1)];
#pragma unroll
  for (int k = 0; k < 8; ++k) z += part[(long)k * (B_ * D_) + i];
  const float g = 1.0f / (1.0f + expf(-z));
  y[i] = x[i] + g * out1[i];
}

// ---------------------------------------------------------------------------
extern "C" void kernel_launch(void* const* d_in, const int* in_sizes, int n_in,
                              void* d_out, int out_size, void* d_ws, size_t ws_size,
                              hipStream_t stream)
{
  const float* x      = (const float*)d_in[0];
  const float* buffer = (const float*)d_in[1];
  const float* Wq     = (const float*)d_in[2];
  const float* Wk     = (const float*)d_in[3];
  const float* Wv     = (const float*)d_in[4];
  const float* Wo     = (const float*)d_in[5];
  const float* Wg     = (const float*)d_in[6];
  const float* bg     = (const float*)d_in[7];
  float* y = (float*)d_out;

  // workspace layout (floats)
  float* ws   = (float*)d_ws;
  float* q    = ws;                      // 128*2048          = 262144
  float* qt   = q    + 262144;           // 128*16*2048       = 4194304
  float* lg   = qt   + 4194304;          // 128*16*512        = 1048576
  float* vt   = lg   + 1048576;          // 128*16*2048       = 4194304
  float* o0   = vt   + 4194304;          // 262144
  float* o1   = o0   + 262144;           // 262144
  float* part = o1   + 262144;           // 8 * 262144        = 2097152

  const long S = B_ * D_;  // 262144, one [B,D] slice

  // 1) q = x @ Wq.T        (K-split 4 -> 256 blocks)
  gemm_tile<<<dim3(32, 2, 4), 256, 0, stream>>>(
      x, D_, 0, Wq, D_, 1, 0, part, D_, 0, S, D_, 4, 1.0f);
  reduce_add_k<<<512, 256, 0, stream>>>(part, 4, S, S, q);

  // 2) qt[b,h,e] = sum_d q[b,h*128+d] * Wk[h*128+d, e]   (batched over h)
  gemm_tile<<<dim3(32, 2, 16), 256, 0, stream>>>(
      q, D_, DH_, Wk, 1, D_, DH_ * D_, qt, H_ * D_, D_, 0, DH_, 1, 1.0f);

  // 3) logits + softmax + vtilde (stream the ring buffer twice)
  logits_k<<<dim3(B_, 2), 256, 0, stream>>>(x, buffer, qt, lg);
  softmax_k<<<B_ * H_, 64, 0, stream>>>(lg);
  vtilde_k<<<dim3(B_, 8), 256, 0, stream>>>(x, buffer, lg, vt);

  // 4) o0[b,h*128+d] = sum_e vt[b,h,e] * Wv[h*128+d, e]  (batched over h, K-split 4)
  gemm_tile<<<dim3(2, 2, H_ * 4), 256, 0, stream>>>(
      vt, H_ * D_, D_, Wv, D_, 1, DH_ * D_, part, D_, DH_, S, D_, 4, 1.0f);
  reduce_add_k<<<512, 256, 0, stream>>>(part, 4, S, S, o0);

  // 5) o1 = o0 @ Wo.T
  gemm_tile<<<dim3(32, 2, 4), 256, 0, stream>>>(
      o0, D_, 0, Wo, D_, 1, 0, part, D_, 0, S, D_, 4, 1.0f);
  reduce_add_k<<<512, 256, 0, stream>>>(part, 4, S, S, o1);

  // 6) gate: z = x@Wg[:, :D].T + o1@Wg[:, D:].T + bg  (slices 0-3 and 4-7)
  gemm_tile<<<dim3(32, 2, 4), 256, 0, stream>>>(
      x, D_, 0, Wg, 2 * D_, 1, 0, part, D_, 0, S, D_, 4, 1.0f);
  gemm_tile<<<dim3(32, 2, 4), 256, 0, stream>>>(
      o1, D_, 0, Wg + D_, 2 * D_, 1, 0, part + 4 * S, D_, 0, S, D_, 4, 1.0f);
  gate_final_k<<<1024, 256, 0, stream>>>(part, bg, x, o1, y);

  (void)in_sizes; (void)n_in; (void)out_size; (void)ws_size;
}

// Round 2
// 503.986 us; speedup vs baseline: 1.1529x; 1.1529x over previous
//
#include <hip/hip_runtime.h>
#include <hip/hip_bf16.h>
#include <math.h>

// Shapes (fixed by the reference)
#define B_   128
#define W_   512
#define D_   2048
#define H_   16
#define DH_  128

typedef __attribute__((ext_vector_type(4))) float f32x4;
typedef __attribute__((ext_vector_type(8))) short bf16x8;

typedef const __attribute__((address_space(1))) void* gvp;
typedef __attribute__((address_space(3))) void* lvp;

__device__ inline short f2bf(float f) {
  union { __hip_bfloat16 h; short s; } u;
  u.h = __float2bfloat16(f);
  return u.s;
}
__device__ inline float bf2f(unsigned short u) {
  return __uint_as_float(((unsigned)u) << 16);
}

// ---------------------------------------------------------------------------
// Generic fp32 GEMM (unchanged from R1): C[ks][batch][m][n] = alpha*sum_k A*B
// ---------------------------------------------------------------------------
#define KC 16
__global__ __launch_bounds__(256) void gemm_tile(
    const float* __restrict__ A, int am, int abatch,
    const float* __restrict__ Bm, int bn, int bk, int bbatch,
    float* __restrict__ C, int cm, int cbatch, long cslice,
    int K, int ksplit, float alpha)
{
  __shared__ float As[64][KC + 1];
  __shared__ float Bs[KC][64 + 1];

  const int t  = threadIdx.x;
  const int tx = t & 15, ty = t >> 4;
  const int n0 = blockIdx.x * 64;
  const int m0 = blockIdx.y * 64;
  const int batch = blockIdx.z / ksplit;
  const int ks    = blockIdx.z % ksplit;
  const int klen  = K / ksplit;
  const int kbeg  = ks * klen;

  const float* Ab = A  + (long)batch * abatch + (long)m0 * am + kbeg;
  const float* Bb = Bm + (long)batch * bbatch + (long)n0 * bn + (long)kbeg * bk;

  float acc[4][4] = {};

  for (int kc = 0; kc < klen; kc += KC) {
#pragma unroll
    for (int i = 0; i < 4; ++i) {
      int idx = i * 256 + t;
      int m = idx >> 4, k = idx & 15;
      As[m][k] = Ab[(long)m * am + kc + k];
    }
    if (bk == 1) {
#pragma unroll
      for (int i = 0; i < 4; ++i) {
        int idx = i * 256 + t;
        int n = idx >> 4, k = idx & 15;
        Bs[k][n] = Bb[(long)n * bn + kc + k];
      }
    } else {
#pragma unroll
      for (int i = 0; i < 4; ++i) {
        int idx = i * 256 + t;
        int k = idx >> 6, n = idx & 63;
        Bs[k][n] = Bb[(long)(kc + k) * bk + n];
      }
    }
    __syncthreads();

#pragma unroll
    for (int kk = 0; kk < KC; ++kk) {
      float a[4], b[4];
#pragma unroll
      for (int i = 0; i < 4; ++i) a[i] = As[ty * 4 + i][kk];
#pragma unroll
      for (int j = 0; j < 4; ++j) b[j] = Bs[kk][tx * 4 + j];
#pragma unroll
      for (int i = 0; i < 4; ++i)
#pragma unroll
        for (int j = 0; j < 4; ++j) acc[i][j] += a[i] * b[j];
    }
    __syncthreads();
  }

  float* Cb = C + (long)ks * cslice + (long)batch * cbatch;
#pragma unroll
  for (int i = 0; i < 4; ++i)
#pragma unroll
    for (int j = 0; j < 4; ++j)
      Cb[(long)(m0 + ty * 4 + i) * cm + (n0 + tx * 4 + j)] = alpha * acc[i][j];
}

__global__ void reduce_add_k(const float* __restrict__ part, int ns, long stride,
                             long n, float* __restrict__ out)
{
  for (long i = (long)blockIdx.x * blockDim.x + threadIdx.x; i < n;
       i += (long)gridDim.x * blockDim.x) {
    float s = 0.f;
    for (int k = 0; k < ns; ++k) s += part[k * stride + i];
    out[i] = s;
  }
}

// ---------------------------------------------------------------------------
// Fused flash attention over the ring-buffer window: ONE pass over buffer.
// grid (128 b, 2 s-halves), block 1024 (16 waves). Wave w owns e-band
// [128w, 128w+128). Ping-pong 8-row fp32 KV tiles in LDS via
// global_load_lds with pre-swizzled source (byte ^= (s&7)<<4).
// logits: mfma 16x16x32 bf16 partial per e-band + ds_add_f32 reduction.
// softmax (online, wave 0). PV: fp32 VALU, 2 e/lane x 16 h accumulators.
// Outputs UNNORMALIZED acc (bf16) + (m,l) per (half,b,h) for combine.
// ---------------------------------------------------------------------------
__global__ __launch_bounds__(1024) void fused_attn(
    const float* __restrict__ x, const float* __restrict__ buffer,
    const float* __restrict__ qt, unsigned short* __restrict__ part,
    float* __restrict__ ml)
{
  __shared__ float kv[2 * 8 * 2048];   // 128 KiB, two 8-row tiles
  __shared__ float lacc[16][9];        // logits accumulator [h][s], padded
  __shared__ float pbuf[16][8];        // softmax p [h][s]
  __shared__ float sbuf[16];           // per-h rescale factor

  const int b    = blockIdx.x;
  const int half = blockIdx.y;
  const int t    = threadIdx.x;
  const int w    = t >> 6;
  const int lane = t & 63;
  const int lo   = lane & 15;
  const int g    = lane >> 4;
  const char* kvb = (const char*)kv;

  // preload q~ A-frags for this wave's e-band (scale folded in), bf16
  bf16x8 afrag[4];
  {
    const float* qrow = qt + ((long)b * H_ + lo) * D_;
    const float sc = 0.088388347648318447f;  // 1/sqrt(128)
#pragma unroll
    for (int kk = 0; kk < 4; ++kk) {
      int e0 = w * 128 + kk * 32 + g * 8;
#pragma unroll
      for (int j = 0; j < 8; ++j) afrag[kk][j] = f2bf(qrow[e0 + j] * sc);
    }
  }

  float accE[16][2];
#pragma unroll
  for (int h = 0; h < 16; ++h) { accE[h][0] = 0.f; accE[h][1] = 0.f; }
  float m_run = -1e30f, l_run = 0.f;   // only wave 0's copy is used

  if (t < 144) ((float*)lacc)[t] = 0.f;

  // stage one 8-row tile (64 KiB) into LDS buffer sb: 4 x 16B per thread.
  // LDS dest is linear (base + lane*16); the source address carries the
  // inverse swizzle so that swizzled LDS reads see row-major data.
  auto stage = [&](int sb, int tl) {
#pragma unroll
    for (int r = 0; r < 4; ++r) {
      int s = r * 2 + (w >> 3);                     // 0..7
      int inrow = (w & 7) * 1024 + lane * 16;       // byte offset in row
      int srco = inrow ^ (s << 4);                  // pre-swizzled source
      int s_glob = half * 256 + tl * 8 + s;
      const float* row = (s_glob < W_ - 1)
          ? buffer + (((long)b * W_ + s_glob + 1) << 11)
          : x + ((long)b << 11);
      __builtin_amdgcn_global_load_lds(
          (gvp)(row + (srco >> 2)),
          (lvp)(kv + sb * 16384 + r * 4096 + w * 256), 16, 0, 0);
    }
  };

  stage(0, 0);
  __syncthreads();

  for (int tile = 0; tile < 32; ++tile) {
    const int buf  = tile & 1;
    const int bufo = buf * 65536;

    // ---- partial logits over this wave's e-band (MFMA)
    f32x4 c = {0.f, 0.f, 0.f, 0.f};
    const int srow = lo & 7;   // cols 8..15 duplicate rows 0..7 (masked out)
#pragma unroll
    for (int kk = 0; kk < 4; ++kk) {
      unsigned B0 = (unsigned)(srow * 8192 + (w * 128 + kk * 32 + g * 8) * 4);
      unsigned o1 = B0 ^ (unsigned)(srow << 4);
      float4 f1 = *(const float4*)(kvb + bufo + o1);
      float4 f2 = *(const float4*)(kvb + bufo + (o1 ^ 16u));
      bf16x8 bf;
      bf[0] = f2bf(f1.x); bf[1] = f2bf(f1.y); bf[2] = f2bf(f1.z); bf[3] = f2bf(f1.w);
      bf[4] = f2bf(f2.x); bf[5] = f2bf(f2.y); bf[6] = f2bf(f2.z); bf[7] = f2bf(f2.w);
      c = __builtin_amdgcn_mfma_f32_16x16x32_bf16(afrag[kk], bf, c, 0, 0, 0);
    }
    if (lo < 8) {
#pragma unroll
      for (int r = 0; r < 4; ++r) atomicAdd(&lacc[g * 4 + r][lo], c[r]);
    }
    __syncthreads();                       // B1: logits complete

    // ---- online softmax (wave 0): lane -> h = lo, s = {2g, 2g+1}
    if (w == 0) {
      float v0 = lacc[lo][g * 2], v1 = lacc[lo][g * 2 + 1];
      float mt = fmaxf(v0, v1);
      mt = fmaxf(mt, __shfl_xor(mt, 16));
      mt = fmaxf(mt, __shfl_xor(mt, 32));
      float m_new = fmaxf(m_run, mt);
      float scl = __expf(m_run - m_new);
      float p0 = __expf(v0 - m_new), p1 = __expf(v1 - m_new);
      float ps = p0 + p1;
      ps += __shfl_xor(ps, 16);
      ps += __shfl_xor(ps, 32);
      l_run = l_run * scl + ps;
      m_run = m_new;
      pbuf[lo][g * 2] = p0; pbuf[lo][g * 2 + 1] = p1;
      if (g == 0) sbuf[lo] = scl;
      lacc[lo][g * 2] = 0.f; lacc[lo][g * 2 + 1] = 0.f;   // zero for next tile
    }
    __syncthreads();                       // B2: pbuf/sbuf ready

    // prefetch next tile NOW so it overlaps the PV phase below
    if (tile + 1 < 32) stage(buf ^ 1, tile + 1);

    // ---- rescale + PV (fp32 VALU). lane owns e = 128w + 2*lane (+1).
    const unsigned ebyte = (unsigned)((w * 128 + lane * 2) * 4);
    float2 kvp[8];
#pragma unroll
    for (int s = 0; s < 8; ++s) {
      unsigned Bv = (unsigned)(s * 8192) + ebyte;
      kvp[s] = *(const float2*)(kvb + bufo + (Bv ^ (unsigned)(s << 4)));
    }
#pragma unroll
    for (int h = 0; h < 16; ++h) {
      float scl = sbuf[h];
      float a0 = accE[h][0] * scl, a1 = accE[h][1] * scl;
      float4 pA = *(const float4*)&pbuf[h][0];
      float4 pB = *(const float4*)&pbuf[h][4];
      a0 += pA.x * kvp[0].x + pA.y * kvp[1].x + pA.z * kvp[2].x + pA.w * kvp[3].x
          + pB.x * kvp[4].x + pB.y * kvp[5].x + pB.z * kvp[6].x + pB.w * kvp[7].x;
      a1 += pA.x * kvp[0].y + pA.y * kvp[1].y + pA.z * kvp[2].y + pA.w * kvp[3].y
          + pB.x * kvp[4].y + pB.y * kvp[5].y + pB.z * kvp[6].y + pB.w * kvp[7].y;
      accE[h][0] = a0; accE[h][1] = a1;
    }
    __syncthreads();                       // B3: PV done; prefetch drained
  }

  // ---- epilogue: unnormalized acc (bf16) + (m,l)
  {
    long base = ((long)half * B_ + b) * H_;
#pragma unroll
    for (int h = 0; h < 16; ++h) {
      long idx = (base + h) * D_ + w * 128 + lane * 2;
      unsigned u0 = (unsigned short)f2bf(accE[h][0]);
      unsigned u1 = (unsigned short)f2bf(accE[h][1]);
      *(unsigned*)(part + idx) = u0 | (u1 << 16);
    }
    if (w == 0 && g == 0) {
      ml[(base + lo) * 2 + 0] = m_run;
      ml[(base + lo) * 2 + 1] = l_run;
    }
  }
}

// ---------------------------------------------------------------------------
// combine the two s-half partials: vt = (w0*acc0 + w1*acc1)/(w0*l0 + w1*l1)
// grid 2048 blocks (= b*16+h), 256 threads, 8 e each.
// ---------------------------------------------------------------------------
__global__ __launch_bounds__(256) void combine_k(
    const unsigned short* __restrict__ part, const float* __restrict__ ml,
    float* __restrict__ vt)
{
  const int bh = blockIdx.x;
  const float m0 = ml[bh * 2],            l0 = ml[bh * 2 + 1];
  const float m1 = ml[(2048 + bh) * 2],   l1 = ml[(2048 + bh) * 2 + 1];
  const float M  = fmaxf(m0, m1);
  const float w0 = __expf(m0 - M), w1 = __expf(m1 - M);
  const float inv = 1.0f / (w0 * l0 + w1 * l1);
  const unsigned short* p0 = part + (long)bh * D_;
  const unsigned short* p1 = part + (long)(2048 + bh) * D_;
  float* out = vt + (long)bh * D_;

  const int e = threadIdx.x * 8;
  ushort4 a1 = *(const ushort4*)(p0 + e);
  ushort4 a2 = *(const ushort4*)(p0 + e + 4);
  ushort4 b1 = *(const ushort4*)(p1 + e);
  ushort4 b2 = *(const ushort4*)(p1 + e + 4);
  float oa[8], ob[8];
  oa[0]=bf2f(a1.x); oa[1]=bf2f(a1.y); oa[2]=bf2f(a1.z); oa[3]=bf2f(a1.w);
  oa[4]=bf2f(a2.x); oa[5]=bf2f(a2.y); oa[6]=bf2f(a2.z); oa[7]=bf2f(a2.w);
  ob[0]=bf2f(b1.x); ob[1]=bf2f(b1.y); ob[2]=bf2f(b1.z); ob[3]=bf2f(b1.w);
  ob[4]=bf2f(b2.x); ob[5]=bf2f(b2.y); ob[6]=bf2f(b2.z); ob[7]=bf2f(b2.w);
#pragma unroll
  for (int j = 0; j < 8; ++j) out[e + j] = (w0 * oa[j] + w1 * ob[j]) * inv;
}

// ---------------------------------------------------------------------------
// gate epilogue (unchanged)
// ---------------------------------------------------------------------------
__global__ __launch_bounds__(256) void gate_final_k(
    const float* __restrict__ part, const float* __restrict__ bg,
    const float* __restrict__ x, const float* __restrict__ out1,
    float* __restrict__ y)
{
  const long i = (long)blockIdx.x * 256 + threadIdx.x;
  float z = bg[i & (D_ - 1)];
#pragma unroll
  for (int k = 0; k < 8; ++k) z += part[(long)k * (B_ * D_) + i];
  const float g = 1.0f / (1.0f + expf(-z));
  y[i] = x[i] + g * out1[i];
}

// ---------------------------------------------------------------------------
extern "C" void kernel_launch(void* const* d_in, const int* in_sizes, int n_in,
                              void* d_out, int out_size, void* d_ws, size_t ws_size,
                              hipStream_t stream)
{
  const float* x      = (const float*)d_in[0];
  const float* buffer = (const float*)d_in[1];
  const float* Wq     = (const float*)d_in[2];
  const float* Wk     = (const float*)d_in[3];
  const float* Wv     = (const float*)d_in[4];
  const float* Wo     = (const float*)d_in[5];
  const float* Wg     = (const float*)d_in[6];
  const float* bg     = (const float*)d_in[7];
  float* y = (float*)d_out;

  // workspace layout (float units)
  float* ws    = (float*)d_ws;
  float* q     = ws;                        // 262144
  float* qt    = ws + 262144;               // 4194304 (vt aliases after fused)
  float* vt    = qt;                        // alias: qt dead once fused done
  unsigned short* part_a = (unsigned short*)(ws + 4456448); // 8388608 bf16
  float* ml    = ws + 8650752;              // 8192
  float* o0    = ws + 8658944;              // 262144
  float* o1    = ws + 8921088;              // 262144
  float* partg = ws + 9183232;              // 2097152

  const long S = (long)B_ * D_;

  // 1) q = x @ Wq.T
  gemm_tile<<<dim3(32, 2, 4), 256, 0, stream>>>(
      x, D_, 0, Wq, D_, 1, 0, partg, D_, 0, S, D_, 4, 1.0f);
  reduce_add_k<<<512, 256, 0, stream>>>(partg, 4, S, S, q);

  // 2) qt[b,h,e] = sum_d q[b,h*128+d] * Wk[h*128+d, e]
  gemm_tile<<<dim3(32, 2, 16), 256, 0, stream>>>(
      q, D_, DH_, Wk, 1, D_, DH_ * D_, qt, H_ * D_, D_, 0, DH_, 1, 1.0f);

  // 3) fused flash attention over the window (single buffer pass) + combine
  fused_attn<<<dim3(B_, 2), 1024, 0, stream>>>(x, buffer, qt, part_a, ml);
  combine_k<<<B_ * H_, 256, 0, stream>>>(part_a, ml, vt);

  // 4) o0[b,h*128+d] = sum_e vt[b,h,e] * Wv[h*128+d, e]
  gemm_tile<<<dim3(2, 2, H_ * 4), 256, 0, stream>>>(
      vt, H_ * D_, D_, Wv, D_, 1, DH_ * D_, partg, D_, DH_, S, D_, 4, 1.0f);
  reduce_add_k<<<512, 256, 0, stream>>>(partg, 4, S, S, o0);

  // 5) o1 = o0 @ Wo.T
  gemm_tile<<<dim3(32, 2, 4), 256, 0, stream>>>(
      o0, D_, 0, Wo, D_, 1, 0, partg, D_, 0, S, D_, 4, 1.0f);
  reduce_add_k<<<512, 256, 0, stream>>>(partg, 4, S, S, o1);

  // 6) gate: z = x@Wg[:, :D].T + o1@Wg[:, D:].T + bg
  gemm_tile<<<dim3(32, 2, 4), 256, 0, stream>>>(
      x, D_, 0, Wg, 2 * D_, 1, 0, partg, D_, 0, S, D_, 4, 1.0f);
  gemm_tile<<<dim3(32, 2, 4), 256, 0, stream>>>(
      o1, D_, 0, Wg + D_, 2 * D_, 1, 0, partg + 4 * S, D_, 0, S, D_, 4, 1.0f);
  gate_final_k<<<1024, 256, 0, stream>>>(partg, bg, x, o1, y);

  (void)in_sizes; (void)n_in; (void)out_size; (void)ws_size;
}

// Round 3
// 321.043 us; speedup vs baseline: 1.8099x; 1.5698x over previous
//
#include <hip/hip_runtime.h>
#include <hip/hip_bf16.h>
#include <math.h>

// Shapes (fixed by the reference)
#define B_   128
#define W_   512
#define D_   2048
#define H_   16
#define DH_  128

typedef __attribute__((ext_vector_type(4))) float f32x4;
typedef __attribute__((ext_vector_type(8))) short bf16x8;

typedef const __attribute__((address_space(1))) void* gvp;
typedef __attribute__((address_space(3))) void* lvp;

__device__ inline short f2bf(float f) {
  union { __hip_bfloat16 h; short s; } u;
  u.h = __float2bfloat16(f);
  return u.s;
}
__device__ inline float bf2f(unsigned short u) {
  return __uint_as_float(((unsigned)u) << 16);
}

// ---------------------------------------------------------------------------
// bf16 MFMA GEMM, M = 128 always.  C[m,n] = sum_k A[m,k] * B[n,k].
// A fp32 (+ optional A2 concat source, switch at k = a2_k; ksplit chunks are
// source-uniform). B fp32 or bf16 (template). Staged to LDS as bf16 with XOR
// swizzle; 4 waves, block tile 128m x 64n, K_STEP = 64, double-buffered.
// grid: (n_tiles, heads, ksplit).  C fp32 at C + ks*c_ks + head*c_hs + n0.
// ---------------------------------------------------------------------------
template<bool BBF16>
__global__ __launch_bounds__(256) void gemm_mfma(
    const float* __restrict__ A, int a_rs, long a_hs,
    const float* __restrict__ A2, int a2_k,
    const void* __restrict__ Bv, int b_rs, long b_hs,
    float* __restrict__ C, int c_rs, long c_hs, long c_ks,
    int Kblk)
{
  __shared__ char sm[2][24576];   // per buf: As[128][64]bf16 (16K) + Bs[64][64] (8K)

  const int t  = threadIdx.x;
  const int w  = t >> 6, l = t & 63, lo = l & 15, hi = l >> 4;
  const int wm = w >> 1, wn = w & 1;
  const int n0   = blockIdx.x * 64;
  const int head = blockIdx.y;
  const int ks   = blockIdx.z;
  const int kbeg = ks * Kblk;
  const int nit  = Kblk >> 6;

  const float* Ab;
  {
    const float* base = A;
    int koff = kbeg;
    if (A2 && kbeg >= a2_k) { base = A2; koff = kbeg - a2_k; }
    Ab = base + head * a_hs + koff;
  }
  const float*          Bf = (const float*)Bv          + (BBF16 ? 0 : head * b_hs + (long)n0 * b_rs + kbeg);
  const unsigned short* Bh = (const unsigned short*)Bv + (BBF16 ? head * b_hs + (long)n0 * b_rs + kbeg : 0);

  const int ar = t >> 2;          // staging row 0..63
  const int ak = (t & 3) * 16;    // staging k offset (elems)

  f32x4 acc[4][2] = {};

  auto load_tiles = [&](int it, float4* ar4, float4* br4) {
    const float* Ait = Ab + it * 64;
#pragma unroll
    for (int p = 0; p < 2; ++p) {
      const float* src = Ait + (long)(p * 64 + ar) * a_rs + ak;
#pragma unroll
      for (int qq = 0; qq < 4; ++qq) ar4[p * 4 + qq] = *(const float4*)(src + qq * 4);
    }
    if (BBF16) {
      const char* src = (const char*)(Bh + (long)ar * b_rs + it * 64 + ak);
      br4[0] = *(const float4*)(src);
      br4[1] = *(const float4*)(src + 16);
    } else {
      const float* src = Bf + (long)ar * b_rs + it * 64 + ak;
#pragma unroll
      for (int qq = 0; qq < 4; ++qq) br4[qq] = *(const float4*)(src + qq * 4);
    }
  };

  auto write_tiles = [&](int buf, const float4* ar4, const float4* br4) {
    char* As = sm[buf];
    char* Bs = sm[buf] + 16384;
#pragma unroll
    for (int p = 0; p < 2; ++p) {
      int m = p * 64 + ar;
      int base = m * 128 + ak * 2;
      int swz = (m & 7) << 4;
#pragma unroll
      for (int h2 = 0; h2 < 2; ++h2) {
        bf16x8 v;
        const float* f = (const float*)(ar4 + p * 4);
#pragma unroll
        for (int j = 0; j < 8; ++j) v[j] = f2bf(f[h2 * 8 + j]);
        *(bf16x8*)(As + ((base + h2 * 16) ^ swz)) = v;
      }
    }
    {
      int n = ar;
      int base = n * 128 + ak * 2;
      int swz = (n & 7) << 4;
      if (BBF16) {
#pragma unroll
        for (int h2 = 0; h2 < 2; ++h2)
          *(bf16x8*)(Bs + ((base + h2 * 16) ^ swz)) = ((const bf16x8*)br4)[h2];
      } else {
#pragma unroll
        for (int h2 = 0; h2 < 2; ++h2) {
          bf16x8 v;
          const float* f = (const float*)br4;
#pragma unroll
          for (int j = 0; j < 8; ++j) v[j] = f2bf(f[h2 * 8 + j]);
          *(bf16x8*)(Bs + ((base + h2 * 16) ^ swz)) = v;
        }
      }
    }
  };

  auto compute = [&](int buf) {
    const char* As = sm[buf];
    const char* Bs = sm[buf] + 16384;
#pragma unroll
    for (int kk = 0; kk < 2; ++kk) {
      bf16x8 af[4], bfr[2];
#pragma unroll
      for (int mi = 0; mi < 4; ++mi) {
        int m = wm * 64 + mi * 16 + lo;
        af[mi] = *(const bf16x8*)(As + ((m * 128 + (kk * 32 + hi * 8) * 2) ^ ((m & 7) << 4)));
      }
#pragma unroll
      for (int ni = 0; ni < 2; ++ni) {
        int n = wn * 32 + ni * 16 + lo;
        bfr[ni] = *(const bf16x8*)(Bs + ((n * 128 + (kk * 32 + hi * 8) * 2) ^ ((n & 7) << 4)));
      }
#pragma unroll
      for (int mi = 0; mi < 4; ++mi)
#pragma unroll
        for (int ni = 0; ni < 2; ++ni)
          acc[mi][ni] = __builtin_amdgcn_mfma_f32_16x16x32_bf16(af[mi], bfr[ni], acc[mi][ni], 0, 0, 0);
    }
  };

  float4 ar4[8], br4[4];
  load_tiles(0, ar4, br4);
  write_tiles(0, ar4, br4);
  __syncthreads();
  for (int it = 0; it < nit; ++it) {
    float4 na[8], nb[4];
    if (it + 1 < nit) load_tiles(it + 1, na, nb);
    compute(it & 1);
    if (it + 1 < nit) write_tiles((it + 1) & 1, na, nb);   // other buffer: safe pre-barrier
    __syncthreads();
  }

  float* Cb = C + c_ks * ks + c_hs * head + n0;
#pragma unroll
  for (int mi = 0; mi < 4; ++mi)
#pragma unroll
    for (int ni = 0; ni < 2; ++ni)
#pragma unroll
      for (int r = 0; r < 4; ++r)
        Cb[(long)(wm * 64 + mi * 16 + hi * 4 + r) * c_rs + (wn * 32 + ni * 16 + lo)] = acc[mi][ni][r];
}

// ---------------------------------------------------------------------------
// WkT[h][e][d] (bf16) = Wk[h*128+d][e].  grid (32 e-tiles, 2 d-tiles, 16 h).
// ---------------------------------------------------------------------------
__global__ __launch_bounds__(256) void transpose_wk(
    const float* __restrict__ Wk, unsigned short* __restrict__ WkT)
{
  __shared__ float tile[64][68];
  const int t  = threadIdx.x;
  const int e0 = blockIdx.x * 64;
  const int d0 = blockIdx.y * 64;
  const int h  = blockIdx.z;
  {
    int d = t >> 2, eq = (t & 3) * 16;
    const float* src = Wk + (long)(h * DH_ + d0 + d) * D_ + e0 + eq;
#pragma unroll
    for (int qq = 0; qq < 4; ++qq)
      *(float4*)&tile[d][eq + qq * 4] = *(const float4*)(src + qq * 4);
  }
  __syncthreads();
  {
    int e = t >> 2, dq = (t & 3) * 16;
    unsigned short* dst = WkT + ((long)h * D_ + e0 + e) * DH_ + d0 + dq;
    bf16x8 v0, v1;
#pragma unroll
    for (int j = 0; j < 8; ++j) v0[j] = f2bf(tile[dq + j][e]);
#pragma unroll
    for (int j = 0; j < 8; ++j) v1[j] = f2bf(tile[dq + 8 + j][e]);
    *(bf16x8*)dst = v0;
    *(bf16x8*)(dst + 8) = v1;
  }
}

// ---------------------------------------------------------------------------
__global__ void reduce_add_k(const float* __restrict__ part, int ns, long stride,
                             long n, float* __restrict__ out)
{
  for (long i = (long)blockIdx.x * blockDim.x + threadIdx.x; i < n;
       i += (long)gridDim.x * blockDim.x) {
    float s = 0.f;
    for (int k = 0; k < ns; ++k) s += part[k * stride + i];
    out[i] = s;
  }
}

// ---------------------------------------------------------------------------
// Fused flash attention (unchanged from R2 — passing, ~bench-dominant)
// ---------------------------------------------------------------------------
__global__ __launch_bounds__(1024) void fused_attn(
    const float* __restrict__ x, const float* __restrict__ buffer,
    const float* __restrict__ qt, unsigned short* __restrict__ part,
    float* __restrict__ ml)
{
  __shared__ float kv[2 * 8 * 2048];
  __shared__ float lacc[16][9];
  __shared__ float pbuf[16][8];
  __shared__ float sbuf[16];

  const int b    = blockIdx.x;
  const int half = blockIdx.y;
  const int t    = threadIdx.x;
  const int w    = t >> 6;
  const int lane = t & 63;
  const int lo   = lane & 15;
  const int g    = lane >> 4;
  const char* kvb = (const char*)kv;

  bf16x8 afrag[4];
  {
    const float* qrow = qt + ((long)b * H_ + lo) * D_;
    const float sc = 0.088388347648318447f;
#pragma unroll
    for (int kk = 0; kk < 4; ++kk) {
      int e0 = w * 128 + kk * 32 + g * 8;
#pragma unroll
      for (int j = 0; j < 8; ++j) afrag[kk][j] = f2bf(qrow[e0 + j] * sc);
    }
  }

  float accE[16][2];
#pragma unroll
  for (int h = 0; h < 16; ++h) { accE[h][0] = 0.f; accE[h][1] = 0.f; }
  float m_run = -1e30f, l_run = 0.f;

  if (t < 144) ((float*)lacc)[t] = 0.f;

  auto stage = [&](int sb, int tl) {
#pragma unroll
    for (int r = 0; r < 4; ++r) {
      int s = r * 2 + (w >> 3);
      int inrow = (w & 7) * 1024 + lane * 16;
      int srco = inrow ^ (s << 4);
      int s_glob = half * 256 + tl * 8 + s;
      const float* row = (s_glob < W_ - 1)
          ? buffer + (((long)b * W_ + s_glob + 1) << 11)
          : x + ((long)b << 11);
      __builtin_amdgcn_global_load_lds(
          (gvp)(row + (srco >> 2)),
          (lvp)(kv + sb * 16384 + r * 4096 + w * 256), 16, 0, 0);
    }
  };

  stage(0, 0);
  __syncthreads();

  for (int tile = 0; tile < 32; ++tile) {
    const int buf  = tile & 1;
    const int bufo = buf * 65536;

    f32x4 c = {0.f, 0.f, 0.f, 0.f};
    const int srow = lo & 7;
#pragma unroll
    for (int kk = 0; kk < 4; ++kk) {
      unsigned B0 = (unsigned)(srow * 8192 + (w * 128 + kk * 32 + g * 8) * 4);
      unsigned o1 = B0 ^ (unsigned)(srow << 4);
      float4 f1 = *(const float4*)(kvb + bufo + o1);
      float4 f2 = *(const float4*)(kvb + bufo + (o1 ^ 16u));
      bf16x8 bf;
      bf[0] = f2bf(f1.x); bf[1] = f2bf(f1.y); bf[2] = f2bf(f1.z); bf[3] = f2bf(f1.w);
      bf[4] = f2bf(f2.x); bf[5] = f2bf(f2.y); bf[6] = f2bf(f2.z); bf[7] = f2bf(f2.w);
      c = __builtin_amdgcn_mfma_f32_16x16x32_bf16(afrag[kk], bf, c, 0, 0, 0);
    }
    if (lo < 8) {
#pragma unroll
      for (int r = 0; r < 4; ++r) atomicAdd(&lacc[g * 4 + r][lo], c[r]);
    }
    __syncthreads();

    if (w == 0) {
      float v0 = lacc[lo][g * 2], v1 = lacc[lo][g * 2 + 1];
      float mt = fmaxf(v0, v1);
      mt = fmaxf(mt, __shfl_xor(mt, 16));
      mt = fmaxf(mt, __shfl_xor(mt, 32));
      float m_new = fmaxf(m_run, mt);
      float scl = __expf(m_run - m_new);
      float p0 = __expf(v0 - m_new), p1 = __expf(v1 - m_new);
      float ps = p0 + p1;
      ps += __shfl_xor(ps, 16);
      ps += __shfl_xor(ps, 32);
      l_run = l_run * scl + ps;
      m_run = m_new;
      pbuf[lo][g * 2] = p0; pbuf[lo][g * 2 + 1] = p1;
      if (g == 0) sbuf[lo] = scl;
      lacc[lo][g * 2] = 0.f; lacc[lo][g * 2 + 1] = 0.f;
    }
    __syncthreads();

    if (tile + 1 < 32) stage(buf ^ 1, tile + 1);

    const unsigned ebyte = (unsigned)((w * 128 + lane * 2) * 4);
    float2 kvp[8];
#pragma unroll
    for (int s = 0; s < 8; ++s) {
      unsigned Bx = (unsigned)(s * 8192) + ebyte;
      kvp[s] = *(const float2*)(kvb + bufo + (Bx ^ (unsigned)(s << 4)));
    }
#pragma unroll
    for (int h = 0; h < 16; ++h) {
      float scl = sbuf[h];
      float a0 = accE[h][0] * scl, a1 = accE[h][1] * scl;
      float4 pA = *(const float4*)&pbuf[h][0];
      float4 pB = *(const float4*)&pbuf[h][4];
      a0 += pA.x * kvp[0].x + pA.y * kvp[1].x + pA.z * kvp[2].x + pA.w * kvp[3].x
          + pB.x * kvp[4].x + pB.y * kvp[5].x + pB.z * kvp[6].x + pB.w * kvp[7].x;
      a1 += pA.x * kvp[0].y + pA.y * kvp[1].y + pA.z * kvp[2].y + pA.w * kvp[3].y
          + pB.x * kvp[4].y + pB.y * kvp[5].y + pB.z * kvp[6].y + pB.w * kvp[7].y;
      accE[h][0] = a0; accE[h][1] = a1;
    }
    __syncthreads();
  }

  {
    long base = ((long)half * B_ + b) * H_;
#pragma unroll
    for (int h = 0; h < 16; ++h) {
      long idx = (base + h) * D_ + w * 128 + lane * 2;
      unsigned u0 = (unsigned short)f2bf(accE[h][0]);
      unsigned u1 = (unsigned short)f2bf(accE[h][1]);
      *(unsigned*)(part + idx) = u0 | (u1 << 16);
    }
    if (w == 0 && g == 0) {
      ml[(base + lo) * 2 + 0] = m_run;
      ml[(base + lo) * 2 + 1] = l_run;
    }
  }
}

// ---------------------------------------------------------------------------
__global__ __launch_bounds__(256) void combine_k(
    const unsigned short* __restrict__ part, const float* __restrict__ ml,
    float* __restrict__ vt)
{
  const int bh = blockIdx.x;
  const float m0 = ml[bh * 2],          l0 = ml[bh * 2 + 1];
  const float m1 = ml[(2048 + bh) * 2], l1 = ml[(2048 + bh) * 2 + 1];
  const float M  = fmaxf(m0, m1);
  const float w0 = __expf(m0 - M), w1 = __expf(m1 - M);
  const float inv = 1.0f / (w0 * l0 + w1 * l1);
  const unsigned short* p0 = part + (long)bh * D_;
  const unsigned short* p1 = part + (long)(2048 + bh) * D_;
  float* out = vt + (long)bh * D_;

  const int e = threadIdx.x * 8;
  ushort4 a1 = *(const ushort4*)(p0 + e);
  ushort4 a2 = *(const ushort4*)(p0 + e + 4);
  ushort4 b1 = *(const ushort4*)(p1 + e);
  ushort4 b2 = *(const ushort4*)(p1 + e + 4);
  float oa[8], ob[8];
  oa[0]=bf2f(a1.x); oa[1]=bf2f(a1.y); oa[2]=bf2f(a1.z); oa[3]=bf2f(a1.w);
  oa[4]=bf2f(a2.x); oa[5]=bf2f(a2.y); oa[6]=bf2f(a2.z); oa[7]=bf2f(a2.w);
  ob[0]=bf2f(b1.x); ob[1]=bf2f(b1.y); ob[2]=bf2f(b1.z); ob[3]=bf2f(b1.w);
  ob[4]=bf2f(b2.x); ob[5]=bf2f(b2.y); ob[6]=bf2f(b2.z); ob[7]=bf2f(b2.w);
#pragma unroll
  for (int j = 0; j < 8; ++j) out[e + j] = (w0 * oa[j] + w1 * ob[j]) * inv;
}

// ---------------------------------------------------------------------------
__global__ __launch_bounds__(256) void gate_final_k(
    const float* __restrict__ part, const float* __restrict__ bg,
    const float* __restrict__ x, const float* __restrict__ out1,
    float* __restrict__ y)
{
  const long i = (long)blockIdx.x * 256 + threadIdx.x;
  float z = bg[i & (D_ - 1)];
#pragma unroll
  for (int k = 0; k < 8; ++k) z += part[(long)k * (B_ * D_) + i];
  const float g = 1.0f / (1.0f + expf(-z));
  y[i] = x[i] + g * out1[i];
}

// ---------------------------------------------------------------------------
extern "C" void kernel_launch(void* const* d_in, const int* in_sizes, int n_in,
                              void* d_out, int out_size, void* d_ws, size_t ws_size,
                              hipStream_t stream)
{
  const float* x      = (const float*)d_in[0];
  const float* buffer = (const float*)d_in[1];
  const float* Wq     = (const float*)d_in[2];
  const float* Wk     = (const float*)d_in[3];
  const float* Wv     = (const float*)d_in[4];
  const float* Wo     = (const float*)d_in[5];
  const float* Wg     = (const float*)d_in[6];
  const float* bg     = (const float*)d_in[7];
  float* y = (float*)d_out;

  // workspace layout (float units)
  float* ws    = (float*)d_ws;
  float* q     = ws;                        // 262144
  float* qt    = ws + 262144;               // 4194304 (vt aliases after fused)
  float* vt    = qt;
  unsigned short* part_a = (unsigned short*)(ws + 4456448); // 8388608 bf16
  float* ml    = ws + 8650752;              // 8192
  float* o0    = ws + 8658944;              // 262144
  float* o1    = ws + 8921088;              // 262144
  float* partg = ws + 9183232;              // 8 * 262144 = 2097152
  unsigned short* wkT = (unsigned short*)(ws + 11280384);   // 16*2048*128 bf16

  const long S = (long)B_ * D_;

  // 0) WkT[h][e][d] bf16
  transpose_wk<<<dim3(32, 2, 16), 256, 0, stream>>>(Wk, wkT);

  // 1) q = x @ Wq.T   (K=2048, ksplit 8)
  gemm_mfma<false><<<dim3(32, 1, 8), 256, 0, stream>>>(
      x, D_, 0, nullptr, 1 << 30, Wq, D_, 0, partg, D_, 0, S, 256);
  reduce_add_k<<<512, 256, 0, stream>>>(partg, 8, S, S, q);

  // 2) qt[b,h,e] = sum_d q[b,h*128+d] * WkT[h][e][d]   (K=128, per-head)
  gemm_mfma<true><<<dim3(32, 16, 1), 256, 0, stream>>>(
      q, D_, DH_, nullptr, 1 << 30, wkT, DH_, (long)D_ * DH_,
      qt, H_ * D_, D_, 0, DH_);

  // 3) fused flash attention + combine
  fused_attn<<<dim3(B_, 2), 1024, 0, stream>>>(x, buffer, qt, part_a, ml);
  combine_k<<<B_ * H_, 256, 0, stream>>>(part_a, ml, vt);

  // 4) o0[b,h*128+d] = sum_e vt[b,h,e] * Wv[h*128+d,e]  (K=2048, per-head n)
  gemm_mfma<false><<<dim3(2, 16, 8), 256, 0, stream>>>(
      vt, H_ * D_, D_, nullptr, 1 << 30, Wv, D_, (long)DH_ * D_,
      partg, D_, DH_, S, 256);
  reduce_add_k<<<512, 256, 0, stream>>>(partg, 8, S, S, o0);

  // 5) o1 = o0 @ Wo.T
  gemm_mfma<false><<<dim3(32, 1, 8), 256, 0, stream>>>(
      o0, D_, 0, nullptr, 1 << 30, Wo, D_, 0, partg, D_, 0, S, 256);
  reduce_add_k<<<512, 256, 0, stream>>>(partg, 8, S, S, o1);

  // 6) gate: z = concat(x,o1) @ Wg.T + bg   (K=4096, A-switch at 2048)
  gemm_mfma<false><<<dim3(32, 1, 8), 256, 0, stream>>>(
      x, D_, 0, o1, D_, Wg, 2 * D_, 0, partg, D_, 0, S, 512);
  gate_final_k<<<1024, 256, 0, stream>>>(partg, bg, x, o1, y);

  (void)in_sizes; (void)n_in; (void)out_size; (void)ws_size;
}

// Round 4
// 312.449 us; speedup vs baseline: 1.8597x; 1.0275x over previous
//
#include <hip/hip_runtime.h>
#include <hip/hip_bf16.h>
#include <math.h>

// Shapes (fixed by the reference)
#define B_   128
#define W_   512
#define D_   2048
#define H_   16
#define DH_  128

typedef __attribute__((ext_vector_type(4))) float f32x4;
typedef __attribute__((ext_vector_type(8))) short bf16x8;

typedef const __attribute__((address_space(1))) void* gvp;
typedef __attribute__((address_space(3))) void* lvp;

__device__ inline short f2bf(float f) {
  union { __hip_bfloat16 h; short s; } u;
  u.h = __float2bfloat16(f);
  return u.s;
}
__device__ inline float bf2f(unsigned short u) {
  return __uint_as_float(((unsigned)u) << 16);
}

// raw barrier: drain LDS ops but NOT in-flight global_load_lds (vmcnt).
// rule #18: sched_barrier(0) fences around the inline-asm wait.
#define LGKM_BARRIER() do {                                   \
    asm volatile("s_waitcnt lgkmcnt(0)" ::: "memory");        \
    __builtin_amdgcn_sched_barrier(0);                        \
    __builtin_amdgcn_s_barrier();                             \
    __builtin_amdgcn_sched_barrier(0);                        \
  } while (0)

// ---------------------------------------------------------------------------
// bf16 MFMA GEMM, M = 128 always.  C[m,n] = sum_k A[m,k] * B[n,k].
// (unchanged from R3)
// ---------------------------------------------------------------------------
template<bool BBF16>
__global__ __launch_bounds__(256) void gemm_mfma(
    const float* __restrict__ A, int a_rs, long a_hs,
    const float* __restrict__ A2, int a2_k,
    const void* __restrict__ Bv, int b_rs, long b_hs,
    float* __restrict__ C, int c_rs, long c_hs, long c_ks,
    int Kblk)
{
  __shared__ char sm[2][24576];

  const int t  = threadIdx.x;
  const int w  = t >> 6, l = t & 63, lo = l & 15, hi = l >> 4;
  const int wm = w >> 1, wn = w & 1;
  const int n0   = blockIdx.x * 64;
  const int head = blockIdx.y;
  const int ks   = blockIdx.z;
  const int kbeg = ks * Kblk;
  const int nit  = Kblk >> 6;

  const float* Ab;
  {
    const float* base = A;
    int koff = kbeg;
    if (A2 && kbeg >= a2_k) { base = A2; koff = kbeg - a2_k; }
    Ab = base + head * a_hs + koff;
  }
  const float*          Bf = (const float*)Bv          + (BBF16 ? 0 : head * b_hs + (long)n0 * b_rs + kbeg);
  const unsigned short* Bh = (const unsigned short*)Bv + (BBF16 ? head * b_hs + (long)n0 * b_rs + kbeg : 0);

  const int ar = t >> 2;
  const int ak = (t & 3) * 16;

  f32x4 acc[4][2] = {};

  auto load_tiles = [&](int it, float4* ar4, float4* br4) {
    const float* Ait = Ab + it * 64;
#pragma unroll
    for (int p = 0; p < 2; ++p) {
      const float* src = Ait + (long)(p * 64 + ar) * a_rs + ak;
#pragma unroll
      for (int qq = 0; qq < 4; ++qq) ar4[p * 4 + qq] = *(const float4*)(src + qq * 4);
    }
    if (BBF16) {
      const char* src = (const char*)(Bh + (long)ar * b_rs + it * 64 + ak);
      br4[0] = *(const float4*)(src);
      br4[1] = *(const float4*)(src + 16);
    } else {
      const float* src = Bf + (long)ar * b_rs + it * 64 + ak;
#pragma unroll
      for (int qq = 0; qq < 4; ++qq) br4[qq] = *(const float4*)(src + qq * 4);
    }
  };

  auto write_tiles = [&](int buf, const float4* ar4, const float4* br4) {
    char* As = sm[buf];
    char* Bs = sm[buf] + 16384;
#pragma unroll
    for (int p = 0; p < 2; ++p) {
      int m = p * 64 + ar;
      int base = m * 128 + ak * 2;
      int swz = (m & 7) << 4;
#pragma unroll
      for (int h2 = 0; h2 < 2; ++h2) {
        bf16x8 v;
        const float* f = (const float*)(ar4 + p * 4);
#pragma unroll
        for (int j = 0; j < 8; ++j) v[j] = f2bf(f[h2 * 8 + j]);
        *(bf16x8*)(As + ((base + h2 * 16) ^ swz)) = v;
      }
    }
    {
      int n = ar;
      int base = n * 128 + ak * 2;
      int swz = (n & 7) << 4;
      if (BBF16) {
#pragma unroll
        for (int h2 = 0; h2 < 2; ++h2)
          *(bf16x8*)(Bs + ((base + h2 * 16) ^ swz)) = ((const bf16x8*)br4)[h2];
      } else {
#pragma unroll
        for (int h2 = 0; h2 < 2; ++h2) {
          bf16x8 v;
          const float* f = (const float*)br4;
#pragma unroll
          for (int j = 0; j < 8; ++j) v[j] = f2bf(f[h2 * 8 + j]);
          *(bf16x8*)(Bs + ((base + h2 * 16) ^ swz)) = v;
        }
      }
    }
  };

  auto compute = [&](int buf) {
    const char* As = sm[buf];
    const char* Bs = sm[buf] + 16384;
#pragma unroll
    for (int kk = 0; kk < 2; ++kk) {
      bf16x8 af[4], bfr[2];
#pragma unroll
      for (int mi = 0; mi < 4; ++mi) {
        int m = wm * 64 + mi * 16 + lo;
        af[mi] = *(const bf16x8*)(As + ((m * 128 + (kk * 32 + hi * 8) * 2) ^ ((m & 7) << 4)));
      }
#pragma unroll
      for (int ni = 0; ni < 2; ++ni) {
        int n = wn * 32 + ni * 16 + lo;
        bfr[ni] = *(const bf16x8*)(Bs + ((n * 128 + (kk * 32 + hi * 8) * 2) ^ ((n & 7) << 4)));
      }
#pragma unroll
      for (int mi = 0; mi < 4; ++mi)
#pragma unroll
        for (int ni = 0; ni < 2; ++ni)
          acc[mi][ni] = __builtin_amdgcn_mfma_f32_16x16x32_bf16(af[mi], bfr[ni], acc[mi][ni], 0, 0, 0);
    }
  };

  float4 ar4[8], br4[4];
  load_tiles(0, ar4, br4);
  write_tiles(0, ar4, br4);
  __syncthreads();
  for (int it = 0; it < nit; ++it) {
    float4 na[8], nb[4];
    if (it + 1 < nit) load_tiles(it + 1, na, nb);
    compute(it & 1);
    if (it + 1 < nit) write_tiles((it + 1) & 1, na, nb);
    __syncthreads();
  }

  float* Cb = C + c_ks * ks + c_hs * head + n0;
#pragma unroll
  for (int mi = 0; mi < 4; ++mi)
#pragma unroll
    for (int ni = 0; ni < 2; ++ni)
#pragma unroll
      for (int r = 0; r < 4; ++r)
        Cb[(long)(wm * 64 + mi * 16 + hi * 4 + r) * c_rs + (wn * 32 + ni * 16 + lo)] = acc[mi][ni][r];
}

// ---------------------------------------------------------------------------
// WkT[h][e][d] (bf16) = Wk[h*128+d][e].  (unchanged)
// ---------------------------------------------------------------------------
__global__ __launch_bounds__(256) void transpose_wk(
    const float* __restrict__ Wk, unsigned short* __restrict__ WkT)
{
  __shared__ float tile[64][68];
  const int t  = threadIdx.x;
  const int e0 = blockIdx.x * 64;
  const int d0 = blockIdx.y * 64;
  const int h  = blockIdx.z;
  {
    int d = t >> 2, eq = (t & 3) * 16;
    const float* src = Wk + (long)(h * DH_ + d0 + d) * D_ + e0 + eq;
#pragma unroll
    for (int qq = 0; qq < 4; ++qq)
      *(float4*)&tile[d][eq + qq * 4] = *(const float4*)(src + qq * 4);
  }
  __syncthreads();
  {
    int e = t >> 2, dq = (t & 3) * 16;
    unsigned short* dst = WkT + ((long)h * D_ + e0 + e) * DH_ + d0 + dq;
    bf16x8 v0, v1;
#pragma unroll
    for (int j = 0; j < 8; ++j) v0[j] = f2bf(tile[dq + j][e]);
#pragma unroll
    for (int j = 0; j < 8; ++j) v1[j] = f2bf(tile[dq + 8 + j][e]);
    *(bf16x8*)dst = v0;
    *(bf16x8*)(dst + 8) = v1;
  }
}

// ---------------------------------------------------------------------------
__global__ void reduce_add_k(const float* __restrict__ part, int ns, long stride,
                             long n, float* __restrict__ out)
{
  for (long i = (long)blockIdx.x * blockDim.x + threadIdx.x; i < n;
       i += (long)gridDim.x * blockDim.x) {
    float s = 0.f;
    for (int k = 0; k < ns; ++k) s += part[k * stride + i];
    out[i] = s;
  }
}

// ---------------------------------------------------------------------------
// Fused flash attention.  R4 change: stage(t+1) issued at TOP of iteration
// (destination buffer free since end of iter t-1), and B1/B2 are raw
// lgkm-only barriers so the in-flight global_load_lds stay in flight across
// the whole iteration.  B3 (__syncthreads) provides the vmcnt(0) drain that
// guarantees tile t+1 is resident before iteration t+1 reads it.
// ---------------------------------------------------------------------------
__global__ __launch_bounds__(1024) void fused_attn(
    const float* __restrict__ x, const float* __restrict__ buffer,
    const float* __restrict__ qt, unsigned short* __restrict__ part,
    float* __restrict__ ml)
{
  __shared__ float kv[2 * 8 * 2048];
  __shared__ float lacc[16][9];
  __shared__ float pbuf[16][8];
  __shared__ float sbuf[16];

  const int b    = blockIdx.x;
  const int half = blockIdx.y;
  const int t    = threadIdx.x;
  const int w    = t >> 6;
  const int lane = t & 63;
  const int lo   = lane & 15;
  const int g    = lane >> 4;
  const char* kvb = (const char*)kv;

  bf16x8 afrag[4];
  {
    const float* qrow = qt + ((long)b * H_ + lo) * D_;
    const float sc = 0.088388347648318447f;
#pragma unroll
    for (int kk = 0; kk < 4; ++kk) {
      int e0 = w * 128 + kk * 32 + g * 8;
#pragma unroll
      for (int j = 0; j < 8; ++j) afrag[kk][j] = f2bf(qrow[e0 + j] * sc);
    }
  }

  float accE[16][2];
#pragma unroll
  for (int h = 0; h < 16; ++h) { accE[h][0] = 0.f; accE[h][1] = 0.f; }
  float m_run = -1e30f, l_run = 0.f;

  if (t < 144) ((float*)lacc)[t] = 0.f;

  auto stage = [&](int sb, int tl) {
#pragma unroll
    for (int r = 0; r < 4; ++r) {
      int s = r * 2 + (w >> 3);
      int inrow = (w & 7) * 1024 + lane * 16;
      int srco = inrow ^ (s << 4);
      int s_glob = half * 256 + tl * 8 + s;
      const float* row = (s_glob < W_ - 1)
          ? buffer + (((long)b * W_ + s_glob + 1) << 11)
          : x + ((long)b << 11);
      __builtin_amdgcn_global_load_lds(
          (gvp)(row + (srco >> 2)),
          (lvp)(kv + sb * 16384 + r * 4096 + w * 256), 16, 0, 0);
    }
  };

  stage(0, 0);
  __syncthreads();

  for (int tile = 0; tile < 32; ++tile) {
    const int buf  = tile & 1;
    const int bufo = buf * 65536;

    // issue next tile's loads NOW: they stay in flight across the whole
    // iteration (B1/B2 do not drain vmcnt), drained at the loop-end B3.
    if (tile + 1 < 32) stage(buf ^ 1, tile + 1);

    // ---- partial logits over this wave's e-band (MFMA)
    f32x4 c = {0.f, 0.f, 0.f, 0.f};
    const int srow = lo & 7;
#pragma unroll
    for (int kk = 0; kk < 4; ++kk) {
      unsigned B0 = (unsigned)(srow * 8192 + (w * 128 + kk * 32 + g * 8) * 4);
      unsigned o1 = B0 ^ (unsigned)(srow << 4);
      float4 f1 = *(const float4*)(kvb + bufo + o1);
      float4 f2 = *(const float4*)(kvb + bufo + (o1 ^ 16u));
      bf16x8 bf;
      bf[0] = f2bf(f1.x); bf[1] = f2bf(f1.y); bf[2] = f2bf(f1.z); bf[3] = f2bf(f1.w);
      bf[4] = f2bf(f2.x); bf[5] = f2bf(f2.y); bf[6] = f2bf(f2.z); bf[7] = f2bf(f2.w);
      c = __builtin_amdgcn_mfma_f32_16x16x32_bf16(afrag[kk], bf, c, 0, 0, 0);
    }
    if (lo < 8) {
#pragma unroll
      for (int r = 0; r < 4; ++r) atomicAdd(&lacc[g * 4 + r][lo], c[r]);
    }
    LGKM_BARRIER();                        // B1: logits complete (lgkm only)

    // ---- online softmax (wave 0)
    if (w == 0) {
      float v0 = lacc[lo][g * 2], v1 = lacc[lo][g * 2 + 1];
      float mt = fmaxf(v0, v1);
      mt = fmaxf(mt, __shfl_xor(mt, 16));
      mt = fmaxf(mt, __shfl_xor(mt, 32));
      float m_new = fmaxf(m_run, mt);
      float scl = __expf(m_run - m_new);
      float p0 = __expf(v0 - m_new), p1 = __expf(v1 - m_new);
      float ps = p0 + p1;
      ps += __shfl_xor(ps, 16);
      ps += __shfl_xor(ps, 32);
      l_run = l_run * scl + ps;
      m_run = m_new;
      pbuf[lo][g * 2] = p0; pbuf[lo][g * 2 + 1] = p1;
      if (g == 0) sbuf[lo] = scl;
      lacc[lo][g * 2] = 0.f; lacc[lo][g * 2 + 1] = 0.f;
    }
    LGKM_BARRIER();                        // B2: pbuf/sbuf ready (lgkm only)

    // ---- rescale + PV (fp32 VALU). lane owns e = 128w + 2*lane (+1).
    const unsigned ebyte = (unsigned)((w * 128 + lane * 2) * 4);
    float2 kvp[8];
#pragma unroll
    for (int s = 0; s < 8; ++s) {
      unsigned Bx = (unsigned)(s * 8192) + ebyte;
      kvp[s] = *(const float2*)(kvb + bufo + (Bx ^ (unsigned)(s << 4)));
    }
#pragma unroll
    for (int h = 0; h < 16; ++h) {
      float scl = sbuf[h];
      float a0 = accE[h][0] * scl, a1 = accE[h][1] * scl;
      float4 pA = *(const float4*)&pbuf[h][0];
      float4 pB = *(const float4*)&pbuf[h][4];
      a0 += pA.x * kvp[0].x + pA.y * kvp[1].x + pA.z * kvp[2].x + pA.w * kvp[3].x
          + pB.x * kvp[4].x + pB.y * kvp[5].x + pB.z * kvp[6].x + pB.w * kvp[7].x;
      a1 += pA.x * kvp[0].y + pA.y * kvp[1].y + pA.z * kvp[2].y + pA.w * kvp[3].y
          + pB.x * kvp[4].y + pB.y * kvp[5].y + pB.z * kvp[6].y + pB.w * kvp[7].y;
      accE[h][0] = a0; accE[h][1] = a1;
    }
    __syncthreads();                       // B3: vmcnt(0) drain -> tile t+1 ready
  }

  {
    long base = ((long)half * B_ + b) * H_;
#pragma unroll
    for (int h = 0; h < 16; ++h) {
      long idx = (base + h) * D_ + w * 128 + lane * 2;
      unsigned u0 = (unsigned short)f2bf(accE[h][0]);
      unsigned u1 = (unsigned short)f2bf(accE[h][1]);
      *(unsigned*)(part + idx) = u0 | (u1 << 16);
    }
    if (w == 0 && g == 0) {
      ml[(base + lo) * 2 + 0] = m_run;
      ml[(base + lo) * 2 + 1] = l_run;
    }
  }
}

// ---------------------------------------------------------------------------
__global__ __launch_bounds__(256) void combine_k(
    const unsigned short* __restrict__ part, const float* __restrict__ ml,
    float* __restrict__ vt)
{
  const int bh = blockIdx.x;
  const float m0 = ml[bh * 2],          l0 = ml[bh * 2 + 1];
  const float m1 = ml[(2048 + bh) * 2], l1 = ml[(2048 + bh) * 2 + 1];
  const float M  = fmaxf(m0, m1);
  const float w0 = __expf(m0 - M), w1 = __expf(m1 - M);
  const float inv = 1.0f / (w0 * l0 + w1 * l1);
  const unsigned short* p0 = part + (long)bh * D_;
  const unsigned short* p1 = part + (long)(2048 + bh) * D_;
  float* out = vt + (long)bh * D_;

  const int e = threadIdx.x * 8;
  ushort4 a1 = *(const ushort4*)(p0 + e);
  ushort4 a2 = *(const ushort4*)(p0 + e + 4);
  ushort4 b1 = *(const ushort4*)(p1 + e);
  ushort4 b2 = *(const ushort4*)(p1 + e + 4);
  float oa[8], ob[8];
  oa[0]=bf2f(a1.x); oa[1]=bf2f(a1.y); oa[2]=bf2f(a1.z); oa[3]=bf2f(a1.w);
  oa[4]=bf2f(a2.x); oa[5]=bf2f(a2.y); oa[6]=bf2f(a2.z); oa[7]=bf2f(a2.w);
  ob[0]=bf2f(b1.x); ob[1]=bf2f(b1.y); ob[2]=bf2f(b1.z); ob[3]=bf2f(b1.w);
  ob[4]=bf2f(b2.x); ob[5]=bf2f(b2.y); ob[6]=bf2f(b2.z); ob[7]=bf2f(b2.w);
#pragma unroll
  for (int j = 0; j < 8; ++j) out[e + j] = (w0 * oa[j] + w1 * ob[j]) * inv;
}

// ---------------------------------------------------------------------------
__global__ __launch_bounds__(256) void gate_final_k(
    const float* __restrict__ part, const float* __restrict__ bg,
    const float* __restrict__ x, const float* __restrict__ out1,
    float* __restrict__ y)
{
  const long i = (long)blockIdx.x * 256 + threadIdx.x;
  float z = bg[i & (D_ - 1)];
#pragma unroll
  for (int k = 0; k < 8; ++k) z += part[(long)k * (B_ * D_) + i];
  const float g = 1.0f / (1.0f + expf(-z));
  y[i] = x[i] + g * out1[i];
}

// ---------------------------------------------------------------------------
extern "C" void kernel_launch(void* const* d_in, const int* in_sizes, int n_in,
                              void* d_out, int out_size, void* d_ws, size_t ws_size,
                              hipStream_t stream)
{
  const float* x      = (const float*)d_in[0];
  const float* buffer = (const float*)d_in[1];
  const float* Wq     = (const float*)d_in[2];
  const float* Wk     = (const float*)d_in[3];
  const float* Wv     = (const float*)d_in[4];
  const float* Wo     = (const float*)d_in[5];
  const float* Wg     = (const float*)d_in[6];
  const float* bg     = (const float*)d_in[7];
  float* y = (float*)d_out;

  // workspace layout (float units)
  float* ws    = (float*)d_ws;
  float* q     = ws;                        // 262144
  float* qt    = ws + 262144;               // 4194304 (vt aliases after fused)
  float* vt    = qt;
  unsigned short* part_a = (unsigned short*)(ws + 4456448); // 8388608 bf16
  float* ml    = ws + 8650752;              // 8192
  float* o0    = ws + 8658944;              // 262144
  float* o1    = ws + 8921088;              // 262144
  float* partg = ws + 9183232;              // 8 * 262144 = 2097152
  unsigned short* wkT = (unsigned short*)(ws + 11280384);   // 16*2048*128 bf16

  const long S = (long)B_ * D_;

  // 0) WkT[h][e][d] bf16
  transpose_wk<<<dim3(32, 2, 16), 256, 0, stream>>>(Wk, wkT);

  // 1) q = x @ Wq.T   (K=2048, ksplit 8)
  gemm_mfma<false><<<dim3(32, 1, 8), 256, 0, stream>>>(
      x, D_, 0, nullptr, 1 << 30, Wq, D_, 0, partg, D_, 0, S, 256);
  reduce_add_k<<<512, 256, 0, stream>>>(partg, 8, S, S, q);

  // 2) qt[b,h,e] = sum_d q[b,h*128+d] * WkT[h][e][d]   (K=128, per-head)
  gemm_mfma<true><<<dim3(32, 16, 1), 256, 0, stream>>>(
      q, D_, DH_, nullptr, 1 << 30, wkT, DH_, (long)D_ * DH_,
      qt, H_ * D_, D_, 0, DH_);

  // 3) fused flash attention + combine
  fused_attn<<<dim3(B_, 2), 1024, 0, stream>>>(x, buffer, qt, part_a, ml);
  combine_k<<<B_ * H_, 256, 0, stream>>>(part_a, ml, vt);

  // 4) o0[b,h*128+d] = sum_e vt[b,h,e] * Wv[h*128+d,e]  (K=2048, per-head n)
  gemm_mfma<false><<<dim3(2, 16, 8), 256, 0, stream>>>(
      vt, H_ * D_, D_, nullptr, 1 << 30, Wv, D_, (long)DH_ * D_,
      partg, D_, DH_, S, 256);
  reduce_add_k<<<512, 256, 0, stream>>>(partg, 8, S, S, o0);

  // 5) o1 = o0 @ Wo.T
  gemm_mfma<false><<<dim3(32, 1, 8), 256, 0, stream>>>(
      o0, D_, 0, nullptr, 1 << 30, Wo, D_, 0, partg, D_, 0, S, 256);
  reduce_add_k<<<512, 256, 0, stream>>>(partg, 8, S, S, o1);

  // 6) gate: z = concat(x,o1) @ Wg.T + bg   (K=4096, A-switch at 2048)
  gemm_mfma<false><<<dim3(32, 1, 8), 256, 0, stream>>>(
      x, D_, 0, o1, D_, Wg, 2 * D_, 0, partg, D_, 0, S, 512);
  gate_final_k<<<1024, 256, 0, stream>>>(partg, bg, x, o1, y);

  (void)in_sizes; (void)n_in; (void)out_size; (void)ws_size;
}